// Round 6
// baseline (127.971 us; speedup 1.0000x reference)
//
#include <hip/hip_runtime.h>
#include <cstdint>
#include <cstddef>

typedef __attribute__((ext_vector_type(8))) short short8;
typedef __attribute__((ext_vector_type(4))) float f32x4;

#define QSCALE 0.18033688011112043f  // 0.125 * log2(e)

__device__ __forceinline__ float bf2f(unsigned short u) {
  return __uint_as_float(((unsigned)u) << 16);
}
__device__ __forceinline__ unsigned short f2bf(float f) {
  unsigned u = __float_as_uint(f);
  u += 0x7fffu + ((u >> 16) & 1u);
  return (unsigned short)(u >> 16);
}
// pack two f32 -> 2 bf16 (RNE) in one VALU op: lo=a, hi=b
__device__ __forceinline__ unsigned cvtpk(float a, float b) {
  unsigned r;
  asm("v_cvt_pk_bf16_f32 %0, %1, %2" : "=v"(r) : "v"(a), "v"(b));
  return r;
}
__device__ __forceinline__ short8 mk8(unsigned a, unsigned b, unsigned c, unsigned d) {
  union { unsigned u[4]; short8 s; } x;
  x.u[0] = a; x.u[1] = b; x.u[2] = c; x.u[3] = d;
  return x.s;
}
__device__ __forceinline__ void g2l16(const void* g, void* l) {
  __builtin_amdgcn_global_load_lds(
      (const __attribute__((address_space(1))) unsigned int*)g,
      (__attribute__((address_space(3))) unsigned int*)l, 16, 0, 0);
}

// ---------------- fused: weight conversion + GroupNorm partial sums ----------------
// blocks [0,1024): f32->bf16 weight convert; blocks [1024,2048): GN partial sums.
__global__ __launch_bounds__(256) void k_wgn(const float* __restrict__ wqf,
                                             const float* __restrict__ wpf,
                                             unsigned short* __restrict__ wq,
                                             unsigned short* __restrict__ wp,
                                             const float* __restrict__ x,
                                             float* __restrict__ part) {
  __shared__ float red[8];
  const int blk = blockIdx.x;
  const int t = threadIdx.x;
  if (blk < 1024) {
    int i = blk * 256 + t;
    if (i < 196608) {
      float4 v = ((const float4*)wqf)[i];
      ushort4 u;
      u.x = f2bf(v.x); u.y = f2bf(v.y); u.z = f2bf(v.z); u.w = f2bf(v.w);
      ((ushort4*)wq)[i] = u;
    } else {
      int k = i - 196608;
      float4 v = ((const float4*)wpf)[k];
      ushort4 u;
      u.x = f2bf(v.x); u.y = f2bf(v.y); u.z = f2bf(v.z); u.w = f2bf(v.w);
      ((ushort4*)wp)[k] = u;
    }
  } else {
    int b2 = blk - 1024;
    int bg = b2 >> 4, slice = b2 & 15;
    const float4* base = (const float4*)(x + (size_t)bg * 65536 + (size_t)slice * 4096);
    float s = 0.f, q = 0.f;
#pragma unroll
    for (int i = 0; i < 4; ++i) {
      float4 v = base[t + i * 256];
      s += v.x + v.y + v.z + v.w;
      q += v.x * v.x + v.y * v.y + v.z * v.z + v.w * v.w;
    }
#pragma unroll
    for (int off = 1; off < 64; off <<= 1) {
      s += __shfl_xor(s, off);
      q += __shfl_xor(q, off);
    }
    int wid = t >> 6;
    if ((t & 63) == 0) { red[wid * 2] = s; red[wid * 2 + 1] = q; }
    __syncthreads();
    if (t == 0) {
      float S = red[0] + red[2] + red[4] + red[6];
      float Q = red[1] + red[3] + red[5] + red[7];
      part[b2 * 2] = S;
      part[b2 * 2 + 1] = Q;
    }
  }
}

// ---------------- GroupNorm stage 2 ----------------
__global__ void k_gnfin(const float* __restrict__ part, float* __restrict__ stats) {
  int t = threadIdx.x;
  float S = 0.f, Q = 0.f;
#pragma unroll
  for (int i = 0; i < 16; ++i) {
    S += part[(t * 16 + i) * 2];
    Q += part[(t * 16 + i) * 2 + 1];
  }
  float mean = S * (1.f / 65536.f);
  float var = Q * (1.f / 65536.f) - mean * mean;
  stats[t * 2] = mean;
  stats[t * 2 + 1] = rsqrtf(var + 1e-6f);
}

// ---------------- GroupNorm normalize: xn + xnT ----------------
__global__ __launch_bounds__(256) void k_gnnorm(const float* __restrict__ x,
                                                const float* __restrict__ gnw,
                                                const float* __restrict__ gnb,
                                                const float* __restrict__ stats,
                                                unsigned short* __restrict__ xn,
                                                unsigned short* __restrict__ xnT) {
  __shared__ float T[64 * 65];
  const int t = threadIdx.x;
  const int n0 = blockIdx.x * 64, c0 = blockIdx.y * 64, bb = blockIdx.z;
#pragma unroll
  for (int p = 0; p < 4; ++p) {
    int s = p * 256 + t;
    int row = s >> 4, seg = s & 15;
    int c = c0 + row;
    int gi = bb * 32 + (c >> 4);
    float mean = stats[gi * 2], rstd = stats[gi * 2 + 1];
    float gw = gnw[c] * rstd;
    float gb = gnb[c] - mean * gw;
    float4 v = *(const float4*)(x + ((size_t)bb * 512 + c) * 4096 + n0 + seg * 4);
    float f0 = v.x * gw + gb, f1 = v.y * gw + gb, f2 = v.z * gw + gb, f3 = v.w * gw + gb;
    ushort4 u;
    u.x = f2bf(f0); u.y = f2bf(f1); u.z = f2bf(f2); u.w = f2bf(f3);
    *(ushort4*)(xn + ((size_t)bb * 512 + c) * 4096 + n0 + seg * 4) = u;
    T[(seg * 4 + 0) * 65 + row] = f0;
    T[(seg * 4 + 1) * 65 + row] = f1;
    T[(seg * 4 + 2) * 65 + row] = f2;
    T[(seg * 4 + 3) * 65 + row] = f3;
  }
  __syncthreads();
#pragma unroll
  for (int p = 0; p < 4; ++p) {
    int s = p * 256 + t;
    int nl = s >> 4, cs = s & 15;
    float f0 = T[nl * 65 + cs * 4 + 0];
    float f1 = T[nl * 65 + cs * 4 + 1];
    float f2 = T[nl * 65 + cs * 4 + 2];
    float f3 = T[nl * 65 + cs * 4 + 3];
    ushort4 u;
    u.x = f2bf(f0); u.y = f2bf(f1); u.z = f2bf(f2); u.w = f2bf(f3);
    *(ushort4*)(xnT + ((size_t)bb * 4096 + n0 + nl) * 512 + c0 + cs * 4) = u;
  }
}

// ---------------- GEMM ----------------
// MODE 0 (QKV): qkv gets V rows only, with j bit-permuted within 64-blocks
//               (u5,u4,u3:2,u1:0 -> u5,u3:2,u4,u1:0) so attn PV reads are b128;
//               qkvT gets Q/K rows only. MODE 1 (proj): +bias+resid f32.
template <int MODE>
__global__ __launch_bounds__(256) void k_gemm(
    const unsigned short* __restrict__ A,
    const unsigned short* __restrict__ Bt,
    const float* __restrict__ bias,
    unsigned short* __restrict__ outA,
    unsigned short* __restrict__ outT,
    const unsigned short* __restrict__ resid,
    float* __restrict__ outF,
    int Mo) {
  __shared__ char lds[34816];
  const int t = threadIdx.x;
  const int lane = t & 63;
  const int g = lane >> 4, ln = lane & 15;
  const int wid = t >> 6, wr = wid >> 1, wc = wid & 1;
  const int bn0 = blockIdx.x * 128, bm0 = blockIdx.y * 128, bb = blockIdx.z;

  const unsigned short* Ab = A + (size_t)bm0 * 512;
  const unsigned short* Bb = Bt + ((size_t)bb * 4096 + bn0) * 512;

  f32x4 acc[4][4];
#pragma unroll
  for (int m = 0; m < 4; ++m)
#pragma unroll
    for (int n = 0; n < 4; ++n) acc[m][n] = f32x4{0.f, 0.f, 0.f, 0.f};

#pragma unroll 1
  for (int kt = 0; kt < 8; ++kt) {
#pragma unroll
    for (int p = 0; p < 4; ++p) {
      int s = p * 256 + t;
      int row = s >> 3;
      int csg = (s & 7) ^ (row & 7);
      g2l16(Ab + (size_t)row * 512 + kt * 64 + csg * 8,
            &lds[(p * 256 + (t & ~63)) * 16]);
    }
#pragma unroll
    for (int p = 0; p < 4; ++p) {
      int s = p * 256 + t;
      int row = s >> 3;
      int csg = (s & 7) ^ (row & 7);
      g2l16(Bb + (size_t)row * 512 + kt * 64 + csg * 8,
            &lds[16384 + (p * 256 + (t & ~63)) * 16]);
    }
    __syncthreads();
#pragma unroll
    for (int kk = 0; kk < 2; ++kk) {
      short8 af[4], bfr[4];
#pragma unroll
      for (int m = 0; m < 4; ++m) {
        int row = wr * 64 + m * 16 + ln;
        int cs = (kk * 4 + g) ^ (row & 7);
        af[m] = *(const short8*)&lds[row * 128 + cs * 16];
      }
#pragma unroll
      for (int n = 0; n < 4; ++n) {
        int row = wc * 64 + n * 16 + ln;
        int cs = (kk * 4 + g) ^ (row & 7);
        bfr[n] = *(const short8*)&lds[16384 + row * 128 + cs * 16];
      }
      __builtin_amdgcn_s_setprio(1);
#pragma unroll
      for (int m = 0; m < 4; ++m)
#pragma unroll
        for (int n = 0; n < 4; ++n)
          acc[m][n] = __builtin_amdgcn_mfma_f32_16x16x32_bf16(af[m], bfr[n], acc[m][n], 0, 0, 0);
      __builtin_amdgcn_s_setprio(0);
    }
    __syncthreads();
  }

  if (MODE == 0) {
#pragma unroll
    for (int m = 0; m < 4; ++m)
#pragma unroll
      for (int n = 0; n < 4; ++n)
#pragma unroll
        for (int r = 0; r < 4; ++r) {
          int ol = wr * 64 + m * 16 + g * 4 + r;
          int jl = wc * 64 + n * 16 + ln;
          int o = bm0 + ol, j = bn0 + jl;
          float v = acc[m][n][r] + bias[o];
          unsigned short bv = f2bf(v);
          if ((o % 192) >= 128) {  // V rows only, j bit-permuted within 64-block
            int jp = (j & ~63) | (j & 32) | ((j & 0xC) << 1) | ((j & 16) >> 2) | (j & 3);
            outA[((size_t)bb * 1536 + o) * 4096 + jp] = bv;
          }
          *(unsigned short*)&lds[jl * 272 + ol * 2] = bv;
        }
    __syncthreads();
#pragma unroll
    for (int p = 0; p < 8; ++p) {
      int s = p * 256 + t;
      int jl = s >> 4, cs = s & 15;
      int oo = bm0 + cs * 8;
      if ((oo % 192) < 128) {  // Q,K rows only
        short8 v = *(const short8*)&lds[jl * 272 + cs * 16];
        *(short8*)&outT[((size_t)bb * 4096 + bn0 + jl) * 1536 + oo] = v;
      }
    }
  } else {
#pragma unroll
    for (int m = 0; m < 4; ++m)
#pragma unroll
      for (int n = 0; n < 4; ++n)
#pragma unroll
        for (int r = 0; r < 4; ++r) {
          int o = bm0 + wr * 64 + m * 16 + g * 4 + r;
          int j = bn0 + wc * 64 + n * 16 + ln;
          size_t idx = ((size_t)bb * 512 + o) * 4096 + j;
          outF[idx] = acc[m][n][r] + bias[o] + bf2f(resid[idx]);
        }
  }
}

// ---------------- Flash attention v10: j-split + fenced exp||PV interleave ----------------
// grid (32 q-tiles of 128, 8 heads, 2 batch) = 512 blocks, 512 threads (8 waves).
// Wave (qw,jw) owns q-subtile 32 x j-slice 32 (v9 structure, halved LDS reads).
// NEW vs v9: PV(jt-1) is deferred (pf/vfp carried in regs) and interleaved with
// exp(jt) as 8 fenced segments {1 PV-MFMA, 2 exp} -- sched_barrier(0) after each
// segment pins the emission order (mask-free; v6's sched_group_barrier VALU mask
// never matched v_exp_f32 = TRANS class, so in-wave MFMA||trans was never tested).
// In-order issue then alternates matrix/trans pipes; across 4 waves/SIMD the
// matrix pipe becomes the pacer instead of phases executing serially.
__global__ __launch_bounds__(512, 4) void k_attn(const unsigned short* __restrict__ qkv,
                                                 const unsigned short* __restrict__ qkvT,
                                                 unsigned short* __restrict__ aT) {
  __shared__ char lds[49152];  // K: cur*8192, V: 24576 + cur*8192
  const int t = threadIdx.x, lane = t & 63;
  const int g = lane >> 4, ln = lane & 15;
  const int wid = t >> 6;   // 0..7
  const int qw = wid >> 1;  // q-subtile 0..3
  const int jw = wid & 1;   // j-slice 0..1
  const int h = blockIdx.y, bb = blockIdx.z;
  const int q0 = blockIdx.x * 128 + qw * 32;

  // K fragment addrs [kk_d][jf]; V fragment addrs [df] (slice jw)
  int kaddr[2][2], vaddr[4];
#pragma unroll
  for (int kk = 0; kk < 2; ++kk)
#pragma unroll
    for (int jf = 0; jf < 2; ++jf) {
      int row = jw * 32 + jf * 16 + ln;
      kaddr[kk][jf] = row * 128 + (((kk * 4 + g) ^ (row & 7)) << 4);
    }
#pragma unroll
  for (int df = 0; df < 4; ++df) {
    int row = df * 16 + ln;
    vaddr[df] = 24576 + row * 128 + (((jw * 4 + g) ^ (row & 7)) << 4);
  }

  // staging source pointers: one K + one V 16B segment per thread per tile
  const unsigned short* kS;
  const unsigned short* vS;
  int ldst;
  {
    int row = t >> 3, csg = (t & 7) ^ (row & 7);
    kS = qkvT + ((size_t)bb * 4096 + row) * 1536 + 192 * h + 64 + csg * 8;
    vS = qkv + ((size_t)bb * 1536 + 192 * h + 128 + row) * 4096 + csg * 8;
    ldst = (t & ~63) * 16;  // wave-uniform base; g2l16 adds lane*16
  }

  // Q fragments [qt][kk_d], pre-scaled by 0.125*log2(e)
  short8 qf[2][2];
#pragma unroll
  for (int qt = 0; qt < 2; ++qt)
#pragma unroll
    for (int kk = 0; kk < 2; ++kk) {
      short8 v = *(const short8*)(qkvT + ((size_t)bb * 4096 + q0 + qt * 16 + ln) * 1536 +
                                  192 * h + kk * 32 + g * 8);
#pragma unroll
      for (int e = 0; e < 8; ++e) {
        float f = bf2f((unsigned short)v[e]) * QSCALE;
        v[e] = (short)f2bf(f);
      }
      qf[qt][kk] = v;
    }

  // all-ones bf16 B fragment for the row-sum MFMA
  const short8 onesb = mk8(0x3F803F80u, 0x3F803F80u, 0x3F803F80u, 0x3F803F80u);

  f32x4 acc[2][4];
  f32x4 lacc[2];
#pragma unroll
  for (int qt = 0; qt < 2; ++qt) {
#pragma unroll
    for (int df = 0; df < 4; ++df) acc[qt][df] = f32x4{0.f, 0.f, 0.f, 0.f};
    lacc[qt] = f32x4{0.f, 0.f, 0.f, 0.f};
  }

  short8 pf[2];    // packed P of previous tile [qt]
  short8 vfp[4];   // V slice fragments of previous tile [df]

  // prologue: stage tiles 0 (buf0) and 1 (buf1)
#pragma unroll
  for (int jt = 0; jt < 2; ++jt) {
    g2l16(kS, &lds[jt * 8192 + ldst]);
    g2l16(vS, &lds[24576 + jt * 8192 + ldst]);
    kS += 64 * 1536;
    vS += 64;
  }

  // ---- peeled iter 0: QK/exp/pack + V read (no PV yet) ----
  {
    asm volatile("s_waitcnt vmcnt(2)" ::: "memory");
    __builtin_amdgcn_s_barrier();
    __builtin_amdgcn_sched_barrier(0);
    g2l16(kS, &lds[2 * 8192 + ldst]);
    g2l16(vS, &lds[24576 + 2 * 8192 + ldst]);
    kS += 64 * 1536;
    vS += 64;
    const char* Kc = &lds[0];
    short8 kf[2][2];
#pragma unroll
    for (int kk = 0; kk < 2; ++kk)
#pragma unroll
      for (int jf = 0; jf < 2; ++jf) kf[kk][jf] = *(const short8*)(Kc + kaddr[kk][jf]);
    const f32x4 zf = f32x4{0.f, 0.f, 0.f, 0.f};
    f32x4 w[2][2];
    __builtin_amdgcn_s_setprio(1);
#pragma unroll
    for (int qt = 0; qt < 2; ++qt)
#pragma unroll
      for (int jf = 0; jf < 2; ++jf)
        w[qt][jf] = __builtin_amdgcn_mfma_f32_16x16x32_bf16(kf[0][jf], qf[qt][0], zf, 0, 0, 0);
#pragma unroll
    for (int qt = 0; qt < 2; ++qt)
#pragma unroll
      for (int jf = 0; jf < 2; ++jf)
        w[qt][jf] = __builtin_amdgcn_mfma_f32_16x16x32_bf16(kf[1][jf], qf[qt][1], w[qt][jf], 0, 0, 0);
    __builtin_amdgcn_s_setprio(0);
#pragma unroll
    for (int qt = 0; qt < 2; ++qt)
#pragma unroll
      for (int jf = 0; jf < 2; ++jf)
#pragma unroll
        for (int r = 0; r < 4; ++r) w[qt][jf][r] = __builtin_amdgcn_exp2f(w[qt][jf][r]);
#pragma unroll
    for (int qt = 0; qt < 2; ++qt)
      pf[qt] = mk8(cvtpk(w[qt][0][0], w[qt][0][1]),
                   cvtpk(w[qt][0][2], w[qt][0][3]),
                   cvtpk(w[qt][1][0], w[qt][1][1]),
                   cvtpk(w[qt][1][2], w[qt][1][3]));
#pragma unroll
    for (int df = 0; df < 4; ++df) vfp[df] = *(const short8*)(Kc + vaddr[df]);
  }

  // ---- main loop: QK(jt) -> [PV(jt-1) || exp(jt)] fenced interleave ----
#pragma unroll 3
  for (int jt = 1; jt < 64; ++jt) {
    const int cur = jt % 3;
    const char* Kc = &lds[cur * 8192];  // vaddr carries the 24576 V base
    if (jt < 63) {
      asm volatile("s_waitcnt vmcnt(2) lgkmcnt(0)" ::: "memory");
    } else {
      asm volatile("s_waitcnt vmcnt(0) lgkmcnt(0)" ::: "memory");
    }
    __builtin_amdgcn_s_barrier();
    __builtin_amdgcn_sched_barrier(0);

    // stage tile jt+2 into buf (jt+2)%3 (safe: all waves passed barrier jt
    // with lgkmcnt(0), so no wave still reads that buffer)
    if (jt < 62) {
      int nb = (jt + 2) % 3;
      g2l16(kS, &lds[nb * 8192 + ldst]);
      g2l16(vS, &lds[24576 + nb * 8192 + ldst]);
      kS += 64 * 1536;
      vS += 64;
    }

    // K slice fragments (4 b128, conflict-free)
    short8 kf[2][2];
#pragma unroll
    for (int kk = 0; kk < 2; ++kk)
#pragma unroll
      for (int jf = 0; jf < 2; ++jf) kf[kk][jf] = *(const short8*)(Kc + kaddr[kk][jf]);

    // QK^T over the slice: w[qt][jf], 8 MFMA, C folded to const zero
    const f32x4 zf = f32x4{0.f, 0.f, 0.f, 0.f};
    f32x4 w[2][2];
    __builtin_amdgcn_s_setprio(1);
#pragma unroll
    for (int qt = 0; qt < 2; ++qt)
#pragma unroll
      for (int jf = 0; jf < 2; ++jf)
        w[qt][jf] = __builtin_amdgcn_mfma_f32_16x16x32_bf16(kf[0][jf], qf[qt][0], zf, 0, 0, 0);
#pragma unroll
    for (int qt = 0; qt < 2; ++qt)
#pragma unroll
      for (int jf = 0; jf < 2; ++jf)
        w[qt][jf] = __builtin_amdgcn_mfma_f32_16x16x32_bf16(kf[1][jf], qf[qt][1], w[qt][jf], 0, 0, 0);
    __builtin_amdgcn_sched_barrier(0);

    // ---- fenced interleave: 8 x {1 PV-MFMA(prev), 2 exp(cur)} ----
#pragma unroll
    for (int s = 0; s < 8; ++s) {
      int pqt = s >> 2, pdf = s & 3;
      acc[pqt][pdf] =
          __builtin_amdgcn_mfma_f32_16x16x32_bf16(pf[pqt], vfp[pdf], acc[pqt][pdf], 0, 0, 0);
      int e0 = 2 * s, e1 = 2 * s + 1;
      w[e0 >> 3][(e0 >> 2) & 1][e0 & 3] =
          __builtin_amdgcn_exp2f(w[e0 >> 3][(e0 >> 2) & 1][e0 & 3]);
      w[e1 >> 3][(e1 >> 2) & 1][e1 & 3] =
          __builtin_amdgcn_exp2f(w[e1 >> 3][(e1 >> 2) & 1][e1 & 3]);
      __builtin_amdgcn_sched_barrier(0);
    }
    // row-sum MFMAs (old pf) then pack new P (overwrites pf after last use)
    lacc[0] = __builtin_amdgcn_mfma_f32_16x16x32_bf16(pf[0], onesb, lacc[0], 0, 0, 0);
    lacc[1] = __builtin_amdgcn_mfma_f32_16x16x32_bf16(pf[1], onesb, lacc[1], 0, 0, 0);
    __builtin_amdgcn_sched_barrier(0);
    __builtin_amdgcn_s_setprio(0);
#pragma unroll
    for (int qt = 0; qt < 2; ++qt)
      pf[qt] = mk8(cvtpk(w[qt][0][0], w[qt][0][1]),
                   cvtpk(w[qt][0][2], w[qt][0][3]),
                   cvtpk(w[qt][1][0], w[qt][1][1]),
                   cvtpk(w[qt][1][2], w[qt][1][3]));
    // read V(jt) for next iteration's PV (buffer cur is not restaged until
    // after barrier jt+1 -> loop-top lgkmcnt(0) fences these reads)
#pragma unroll
    for (int df = 0; df < 4; ++df) vfp[df] = *(const short8*)(Kc + vaddr[df]);
  }

  // ---- drain: PV + row-sum for tile 63 ----
  __builtin_amdgcn_s_setprio(1);
#pragma unroll
  for (int qt = 0; qt < 2; ++qt) {
#pragma unroll
    for (int df = 0; df < 4; ++df)
      acc[qt][df] = __builtin_amdgcn_mfma_f32_16x16x32_bf16(pf[qt], vfp[df], acc[qt][df], 0, 0, 0);
    lacc[qt] = __builtin_amdgcn_mfma_f32_16x16x32_bf16(pf[qt], onesb, lacc[qt], 0, 0, 0);
  }
  __builtin_amdgcn_s_setprio(0);

  // ---- epilogue: combine jw partials via LDS (reuse K/V buffers), then write ----
  __syncthreads();
  float* cb = (float*)lds;
  const int cbase = qw * 2560;  // floats; 10240 B per qw, 40960 B total
  if (jw == 1) {
#pragma unroll
    for (int qt = 0; qt < 2; ++qt) {
#pragma unroll
      for (int df = 0; df < 4; ++df)
        *(f32x4*)&cb[cbase + ((qt * 4 + df) * 64 + lane) * 4] = acc[qt][df];
      *(f32x4*)&cb[cbase + 2048 + (qt * 64 + lane) * 4] = lacc[qt];
    }
  }
  __syncthreads();
  if (jw == 0) {
#pragma unroll
    for (int qt = 0; qt < 2; ++qt) {
#pragma unroll
      for (int df = 0; df < 4; ++df)
        acc[qt][df] += *(const f32x4*)&cb[cbase + ((qt * 4 + df) * 64 + lane) * 4];
      lacc[qt] += *(const f32x4*)&cb[cbase + 2048 + (qt * 64 + lane) * 4];
    }
#pragma unroll
    for (int qt = 0; qt < 2; ++qt)
#pragma unroll
      for (int r = 0; r < 4; ++r) {
        float inv = 1.f / lacc[qt][r];
        int row = q0 + qt * 16 + g * 4 + r;
#pragma unroll
        for (int df = 0; df < 4; ++df)
          aT[((size_t)bb * 4096 + row) * 512 + h * 64 + df * 16 + ln] =
              f2bf(acc[qt][df][r] * inv);
      }
  }
}

// ---------------- launcher ----------------
extern "C" void kernel_launch(void* const* d_in, const int* in_sizes, int n_in,
                              void* d_out, int out_size, void* d_ws, size_t ws_size,
                              hipStream_t stream) {
  const float* x     = (const float*)d_in[0];
  const float* gnw   = (const float*)d_in[1];
  const float* gnb   = (const float*)d_in[2];
  const float* qkvw  = (const float*)d_in[3];
  const float* qkvb  = (const float*)d_in[4];
  const float* projw = (const float*)d_in[5];
  const float* projb = (const float*)d_in[6];
  float* out = (float*)d_out;
  char* ws = (char*)d_ws;

  const size_t OFF_WQ   = 0;
  const size_t OFF_WP   = 1572864;
  const size_t OFF_XN   = 2097152;
  const size_t OFF_XNT  = 10485760;
  const size_t OFF_QKV  = 18874368;
  const size_t OFF_QKVT = 44040192;
  const size_t OFF_AT   = 69206016;
  const size_t OFF_PART = 77594624;
  const size_t OFF_STAT = 77602816;

  unsigned short* wq   = (unsigned short*)(ws + OFF_WQ);
  unsigned short* wp   = (unsigned short*)(ws + OFF_WP);
  unsigned short* xn   = (unsigned short*)(ws + OFF_XN);
  unsigned short* xnT  = (unsigned short*)(ws + OFF_XNT);
  unsigned short* qkv  = (unsigned short*)(ws + OFF_QKV);
  unsigned short* qkvT = (unsigned short*)(ws + OFF_QKVT);
  unsigned short* aT   = (unsigned short*)(ws + OFF_AT);
  float* part  = (float*)(ws + OFF_PART);
  float* stats = (float*)(ws + OFF_STAT);

  k_wgn<<<dim3(2048), dim3(256), 0, stream>>>(qkvw, projw, wq, wp, x, part);
  k_gnfin<<<dim3(1), dim3(64), 0, stream>>>(part, stats);
  k_gnnorm<<<dim3(64, 8, 2), dim3(256), 0, stream>>>(x, gnw, gnb, stats, xn, xnT);
  k_gemm<0><<<dim3(32, 12, 2), dim3(256), 0, stream>>>(wq, xnT, qkvb, qkv, qkvT, nullptr, nullptr, 1536);
  k_attn<<<dim3(32, 8, 2), dim3(512), 0, stream>>>(qkv, qkvT, aT);
  k_gemm<1><<<dim3(32, 4, 2), dim3(256), 0, stream>>>(wp, aT, projb, nullptr, nullptr, xn, out, 512);
}

// Round 7
// 124.919 us; speedup vs baseline: 1.0244x; 1.0244x over previous
//
#include <hip/hip_runtime.h>
#include <cstdint>
#include <cstddef>

typedef __attribute__((ext_vector_type(8))) short short8;
typedef __attribute__((ext_vector_type(4))) float f32x4;

#define QSCALE 0.18033688011112043f  // 0.125 * log2(e)

__device__ __forceinline__ float bf2f(unsigned short u) {
  return __uint_as_float(((unsigned)u) << 16);
}
__device__ __forceinline__ unsigned short f2bf(float f) {
  unsigned u = __float_as_uint(f);
  u += 0x7fffu + ((u >> 16) & 1u);
  return (unsigned short)(u >> 16);
}
// pack two f32 -> 2 bf16 (RNE) in one VALU op: lo=a, hi=b
__device__ __forceinline__ unsigned cvtpk(float a, float b) {
  unsigned r;
  asm("v_cvt_pk_bf16_f32 %0, %1, %2" : "=v"(r) : "v"(a), "v"(b));
  return r;
}
__device__ __forceinline__ short8 mk8(unsigned a, unsigned b, unsigned c, unsigned d) {
  union { unsigned u[4]; short8 s; } x;
  x.u[0] = a; x.u[1] = b; x.u[2] = c; x.u[3] = d;
  return x.s;
}
__device__ __forceinline__ void g2l16(const void* g, void* l) {
  __builtin_amdgcn_global_load_lds(
      (const __attribute__((address_space(1))) unsigned int*)g,
      (__attribute__((address_space(3))) unsigned int*)l, 16, 0, 0);
}

// ---------------- fused: weight conversion + GroupNorm partial sums ----------------
// blocks [0,1024): f32->bf16 weight convert; blocks [1024,2048): GN partial sums.
__global__ __launch_bounds__(256) void k_wgn(const float* __restrict__ wqf,
                                             const float* __restrict__ wpf,
                                             unsigned short* __restrict__ wq,
                                             unsigned short* __restrict__ wp,
                                             const float* __restrict__ x,
                                             float* __restrict__ part) {
  __shared__ float red[8];
  const int blk = blockIdx.x;
  const int t = threadIdx.x;
  if (blk < 1024) {
    int i = blk * 256 + t;
    if (i < 196608) {
      float4 v = ((const float4*)wqf)[i];
      ushort4 u;
      u.x = f2bf(v.x); u.y = f2bf(v.y); u.z = f2bf(v.z); u.w = f2bf(v.w);
      ((ushort4*)wq)[i] = u;
    } else {
      int k = i - 196608;
      float4 v = ((const float4*)wpf)[k];
      ushort4 u;
      u.x = f2bf(v.x); u.y = f2bf(v.y); u.z = f2bf(v.z); u.w = f2bf(v.w);
      ((ushort4*)wp)[k] = u;
    }
  } else {
    int b2 = blk - 1024;
    int bg = b2 >> 4, slice = b2 & 15;
    const float4* base = (const float4*)(x + (size_t)bg * 65536 + (size_t)slice * 4096);
    float s = 0.f, q = 0.f;
#pragma unroll
    for (int i = 0; i < 4; ++i) {
      float4 v = base[t + i * 256];
      s += v.x + v.y + v.z + v.w;
      q += v.x * v.x + v.y * v.y + v.z * v.z + v.w * v.w;
    }
#pragma unroll
    for (int off = 1; off < 64; off <<= 1) {
      s += __shfl_xor(s, off);
      q += __shfl_xor(q, off);
    }
    int wid = t >> 6;
    if ((t & 63) == 0) { red[wid * 2] = s; red[wid * 2 + 1] = q; }
    __syncthreads();
    if (t == 0) {
      float S = red[0] + red[2] + red[4] + red[6];
      float Q = red[1] + red[3] + red[5] + red[7];
      part[b2 * 2] = S;
      part[b2 * 2 + 1] = Q;
    }
  }
}

// ---------------- GroupNorm stage 2 ----------------
__global__ void k_gnfin(const float* __restrict__ part, float* __restrict__ stats) {
  int t = threadIdx.x;
  float S = 0.f, Q = 0.f;
#pragma unroll
  for (int i = 0; i < 16; ++i) {
    S += part[(t * 16 + i) * 2];
    Q += part[(t * 16 + i) * 2 + 1];
  }
  float mean = S * (1.f / 65536.f);
  float var = Q * (1.f / 65536.f) - mean * mean;
  stats[t * 2] = mean;
  stats[t * 2 + 1] = rsqrtf(var + 1e-6f);
}

// ---------------- GroupNorm normalize: xn + xnT ----------------
__global__ __launch_bounds__(256) void k_gnnorm(const float* __restrict__ x,
                                                const float* __restrict__ gnw,
                                                const float* __restrict__ gnb,
                                                const float* __restrict__ stats,
                                                unsigned short* __restrict__ xn,
                                                unsigned short* __restrict__ xnT) {
  __shared__ float T[64 * 65];
  const int t = threadIdx.x;
  const int n0 = blockIdx.x * 64, c0 = blockIdx.y * 64, bb = blockIdx.z;
#pragma unroll
  for (int p = 0; p < 4; ++p) {
    int s = p * 256 + t;
    int row = s >> 4, seg = s & 15;
    int c = c0 + row;
    int gi = bb * 32 + (c >> 4);
    float mean = stats[gi * 2], rstd = stats[gi * 2 + 1];
    float gw = gnw[c] * rstd;
    float gb = gnb[c] - mean * gw;
    float4 v = *(const float4*)(x + ((size_t)bb * 512 + c) * 4096 + n0 + seg * 4);
    float f0 = v.x * gw + gb, f1 = v.y * gw + gb, f2 = v.z * gw + gb, f3 = v.w * gw + gb;
    ushort4 u;
    u.x = f2bf(f0); u.y = f2bf(f1); u.z = f2bf(f2); u.w = f2bf(f3);
    *(ushort4*)(xn + ((size_t)bb * 512 + c) * 4096 + n0 + seg * 4) = u;
    T[(seg * 4 + 0) * 65 + row] = f0;
    T[(seg * 4 + 1) * 65 + row] = f1;
    T[(seg * 4 + 2) * 65 + row] = f2;
    T[(seg * 4 + 3) * 65 + row] = f3;
  }
  __syncthreads();
#pragma unroll
  for (int p = 0; p < 4; ++p) {
    int s = p * 256 + t;
    int nl = s >> 4, cs = s & 15;
    float f0 = T[nl * 65 + cs * 4 + 0];
    float f1 = T[nl * 65 + cs * 4 + 1];
    float f2 = T[nl * 65 + cs * 4 + 2];
    float f3 = T[nl * 65 + cs * 4 + 3];
    ushort4 u;
    u.x = f2bf(f0); u.y = f2bf(f1); u.z = f2bf(f2); u.w = f2bf(f3);
    *(ushort4*)(xnT + ((size_t)bb * 4096 + n0 + nl) * 512 + c0 + cs * 4) = u;
  }
}

// ---------------- GEMM ----------------
// MODE 0 (QKV): qkv gets V rows only, with j bit-permuted within 64-blocks
//               (u5,u4,u3:2,u1:0 -> u5,u3:2,u4,u1:0) so attn PV reads are b128;
//               qkvT gets Q/K rows only. MODE 1 (proj): +bias+resid f32.
template <int MODE>
__global__ __launch_bounds__(256) void k_gemm(
    const unsigned short* __restrict__ A,
    const unsigned short* __restrict__ Bt,
    const float* __restrict__ bias,
    unsigned short* __restrict__ outA,
    unsigned short* __restrict__ outT,
    const unsigned short* __restrict__ resid,
    float* __restrict__ outF,
    int Mo) {
  __shared__ char lds[34816];
  const int t = threadIdx.x;
  const int lane = t & 63;
  const int g = lane >> 4, ln = lane & 15;
  const int wid = t >> 6, wr = wid >> 1, wc = wid & 1;
  const int bn0 = blockIdx.x * 128, bm0 = blockIdx.y * 128, bb = blockIdx.z;

  const unsigned short* Ab = A + (size_t)bm0 * 512;
  const unsigned short* Bb = Bt + ((size_t)bb * 4096 + bn0) * 512;

  f32x4 acc[4][4];
#pragma unroll
  for (int m = 0; m < 4; ++m)
#pragma unroll
    for (int n = 0; n < 4; ++n) acc[m][n] = f32x4{0.f, 0.f, 0.f, 0.f};

#pragma unroll 1
  for (int kt = 0; kt < 8; ++kt) {
#pragma unroll
    for (int p = 0; p < 4; ++p) {
      int s = p * 256 + t;
      int row = s >> 3;
      int csg = (s & 7) ^ (row & 7);
      g2l16(Ab + (size_t)row * 512 + kt * 64 + csg * 8,
            &lds[(p * 256 + (t & ~63)) * 16]);
    }
#pragma unroll
    for (int p = 0; p < 4; ++p) {
      int s = p * 256 + t;
      int row = s >> 3;
      int csg = (s & 7) ^ (row & 7);
      g2l16(Bb + (size_t)row * 512 + kt * 64 + csg * 8,
            &lds[16384 + (p * 256 + (t & ~63)) * 16]);
    }
    __syncthreads();
#pragma unroll
    for (int kk = 0; kk < 2; ++kk) {
      short8 af[4], bfr[4];
#pragma unroll
      for (int m = 0; m < 4; ++m) {
        int row = wr * 64 + m * 16 + ln;
        int cs = (kk * 4 + g) ^ (row & 7);
        af[m] = *(const short8*)&lds[row * 128 + cs * 16];
      }
#pragma unroll
      for (int n = 0; n < 4; ++n) {
        int row = wc * 64 + n * 16 + ln;
        int cs = (kk * 4 + g) ^ (row & 7);
        bfr[n] = *(const short8*)&lds[16384 + row * 128 + cs * 16];
      }
      __builtin_amdgcn_s_setprio(1);
#pragma unroll
      for (int m = 0; m < 4; ++m)
#pragma unroll
        for (int n = 0; n < 4; ++n)
          acc[m][n] = __builtin_amdgcn_mfma_f32_16x16x32_bf16(af[m], bfr[n], acc[m][n], 0, 0, 0);
      __builtin_amdgcn_s_setprio(0);
    }
    __syncthreads();
  }

  if (MODE == 0) {
#pragma unroll
    for (int m = 0; m < 4; ++m)
#pragma unroll
      for (int n = 0; n < 4; ++n)
#pragma unroll
        for (int r = 0; r < 4; ++r) {
          int ol = wr * 64 + m * 16 + g * 4 + r;
          int jl = wc * 64 + n * 16 + ln;
          int o = bm0 + ol, j = bn0 + jl;
          float v = acc[m][n][r] + bias[o];
          unsigned short bv = f2bf(v);
          if ((o % 192) >= 128) {  // V rows only, j bit-permuted within 64-block
            int jp = (j & ~63) | (j & 32) | ((j & 0xC) << 1) | ((j & 16) >> 2) | (j & 3);
            outA[((size_t)bb * 1536 + o) * 4096 + jp] = bv;
          }
          *(unsigned short*)&lds[jl * 272 + ol * 2] = bv;
        }
    __syncthreads();
#pragma unroll
    for (int p = 0; p < 8; ++p) {
      int s = p * 256 + t;
      int jl = s >> 4, cs = s & 15;
      int oo = bm0 + cs * 8;
      if ((oo % 192) < 128) {  // Q,K rows only
        short8 v = *(const short8*)&lds[jl * 272 + cs * 16];
        *(short8*)&outT[((size_t)bb * 4096 + bn0 + jl) * 1536 + oo] = v;
      }
    }
  } else {
#pragma unroll
    for (int m = 0; m < 4; ++m)
#pragma unroll
      for (int n = 0; n < 4; ++n)
#pragma unroll
        for (int r = 0; r < 4; ++r) {
          int o = bm0 + wr * 64 + m * 16 + g * 4 + r;
          int j = bn0 + wc * 64 + n * 16 + ln;
          size_t idx = ((size_t)bb * 512 + o) * 4096 + j;
          outF[idx] = acc[m][n][r] + bias[o] + bf2f(resid[idx]);
        }
  }
}

// ---------------- Flash attention v11: 4 waves x 64 q-rows, LDS reads halved again ----------------
// grid (32 q-tiles of 128, 8 heads, 2 batch) = 512 blocks, 256 threads (4 waves).
// Wave (qw=wid>>1, jw=wid&1) owns q-subtile qw*64 (64 rows, qt=0..3) x j-slice
// jw*32. LDS-read algebra: reads/block-iter = 16KB x (128 / q_rows_per_wave) --
// independent of j-split. v9 (q_w=32): 64KB/block; HERE (q_w=64): 32KB/block ->
// 64 KB/CU/iter, half of v9, below the matrix pipe (~1400 cyc/CU/iter) for the
// first time. MFMA/exp/staging totals unchanged. VGPR ~220 -> 2 waves/SIMD
// (v5 vs v7 showed 2 vs 4 waves/SIMD is ~neutral; LDS traffic is what pays).
// v9 straight body (no deferred-PV interleave -- v6/v8/v10 all proved null).
__global__ __launch_bounds__(256, 2) void k_attn(const unsigned short* __restrict__ qkv,
                                                 const unsigned short* __restrict__ qkvT,
                                                 unsigned short* __restrict__ aT) {
  __shared__ char lds[49152];  // K: cur*8192, V: 24576 + cur*8192
  const int t = threadIdx.x, lane = t & 63;
  const int g = lane >> 4, ln = lane & 15;
  const int wid = t >> 6;   // 0..3
  const int qw = wid >> 1;  // q-subtile 0..1 (64 rows each)
  const int jw = wid & 1;   // j-slice 0..1
  const int h = blockIdx.y, bb = blockIdx.z;
  const int q0 = blockIdx.x * 128 + qw * 64;

  // K fragment addrs [kk_d][jf]; V fragment addrs [df] (slice jw)
  int kaddr[2][2], vaddr[4];
#pragma unroll
  for (int kk = 0; kk < 2; ++kk)
#pragma unroll
    for (int jf = 0; jf < 2; ++jf) {
      int row = jw * 32 + jf * 16 + ln;
      kaddr[kk][jf] = row * 128 + (((kk * 4 + g) ^ (row & 7)) << 4);
    }
#pragma unroll
  for (int df = 0; df < 4; ++df) {
    int row = df * 16 + ln;
    vaddr[df] = 24576 + row * 128 + (((jw * 4 + g) ^ (row & 7)) << 4);
  }

  // staging: 256 threads x 2 segments cover each 8KB tile (K and V)
  const unsigned short* kS[2];
  const unsigned short* vS[2];
  int ldst[2];
#pragma unroll
  for (int p = 0; p < 2; ++p) {
    int s = p * 256 + t;
    int row = s >> 3, csg = (s & 7) ^ (row & 7);
    kS[p] = qkvT + ((size_t)bb * 4096 + row) * 1536 + 192 * h + 64 + csg * 8;
    vS[p] = qkv + ((size_t)bb * 1536 + 192 * h + 128 + row) * 4096 + csg * 8;
    ldst[p] = (p * 256 + (t & ~63)) * 16;  // wave-uniform base; g2l16 adds lane*16
  }

  // Q fragments [qt][kk_d], pre-scaled by 0.125*log2(e)
  short8 qf[4][2];
#pragma unroll
  for (int qt = 0; qt < 4; ++qt)
#pragma unroll
    for (int kk = 0; kk < 2; ++kk) {
      short8 v = *(const short8*)(qkvT + ((size_t)bb * 4096 + q0 + qt * 16 + ln) * 1536 +
                                  192 * h + kk * 32 + g * 8);
#pragma unroll
      for (int e = 0; e < 8; ++e) {
        float f = bf2f((unsigned short)v[e]) * QSCALE;
        v[e] = (short)f2bf(f);
      }
      qf[qt][kk] = v;
    }

  // all-ones bf16 B fragment for the row-sum MFMA
  const short8 onesb = mk8(0x3F803F80u, 0x3F803F80u, 0x3F803F80u, 0x3F803F80u);

  f32x4 acc[4][4];
  f32x4 lacc[4];
#pragma unroll
  for (int qt = 0; qt < 4; ++qt) {
#pragma unroll
    for (int df = 0; df < 4; ++df) acc[qt][df] = f32x4{0.f, 0.f, 0.f, 0.f};
    lacc[qt] = f32x4{0.f, 0.f, 0.f, 0.f};
  }

  // prologue: stage tiles 0 (buf0) and 1 (buf1): 8 loads
#pragma unroll
  for (int jt = 0; jt < 2; ++jt) {
#pragma unroll
    for (int p = 0; p < 2; ++p) {
      g2l16(kS[p], &lds[jt * 8192 + ldst[p]]);
      g2l16(vS[p], &lds[24576 + jt * 8192 + ldst[p]]);
      kS[p] += 64 * 1536;
      vS[p] += 64;
    }
  }

  // ---- main loop: QK(slice) -> exp -> pack -> PV(slice), all in-iteration ----
#pragma unroll 3
  for (int jt = 0; jt < 64; ++jt) {
    const int cur = jt % 3;
    const char* Kc = &lds[cur * 8192];  // vaddr carries the 24576 V base
    if (jt < 63) {
      asm volatile("s_waitcnt vmcnt(4) lgkmcnt(0)" ::: "memory");
    } else {
      asm volatile("s_waitcnt vmcnt(0) lgkmcnt(0)" ::: "memory");
    }
    __builtin_amdgcn_s_barrier();
    __builtin_amdgcn_sched_barrier(0);

    // stage tile jt+2 into buf (jt+2)%3 (safe: all waves passed barrier jt
    // with lgkmcnt(0), so no wave still reads that buffer)
    if (jt < 62) {
      int nb = (jt + 2) % 3;
#pragma unroll
      for (int p = 0; p < 2; ++p) {
        g2l16(kS[p], &lds[nb * 8192 + ldst[p]]);
        g2l16(vS[p], &lds[24576 + nb * 8192 + ldst[p]]);
        kS[p] += 64 * 1536;
        vS[p] += 64;
      }
    }

    // K slice fragments (4 b128, conflict-free)
    short8 kf[2][2];
#pragma unroll
    for (int kk = 0; kk < 2; ++kk)
#pragma unroll
      for (int jf = 0; jf < 2; ++jf) kf[kk][jf] = *(const short8*)(Kc + kaddr[kk][jf]);

    // QK^T over the slice: w[qt][jf], 16 MFMA, C folded to const zero
    const f32x4 zf = f32x4{0.f, 0.f, 0.f, 0.f};
    f32x4 w[4][2];
    __builtin_amdgcn_s_setprio(1);
#pragma unroll
    for (int qt = 0; qt < 4; ++qt)
#pragma unroll
      for (int jf = 0; jf < 2; ++jf)
        w[qt][jf] = __builtin_amdgcn_mfma_f32_16x16x32_bf16(kf[0][jf], qf[qt][0], zf, 0, 0, 0);
#pragma unroll
    for (int qt = 0; qt < 4; ++qt)
#pragma unroll
      for (int jf = 0; jf < 2; ++jf)
        w[qt][jf] = __builtin_amdgcn_mfma_f32_16x16x32_bf16(kf[1][jf], qf[qt][1], w[qt][jf], 0, 0, 0);
    __builtin_amdgcn_s_setprio(0);

    // V slice fragments (4 b128) -- issued before exp so ds latency hides there
    short8 vf[4];
#pragma unroll
    for (int df = 0; df < 4; ++df) vf[df] = *(const short8*)(Kc + vaddr[df]);

    // p = exp2(w), 32 trans ops
#pragma unroll
    for (int qt = 0; qt < 4; ++qt)
#pragma unroll
      for (int jf = 0; jf < 2; ++jf)
#pragma unroll
        for (int r = 0; r < 4; ++r) w[qt][jf][r] = __builtin_amdgcn_exp2f(w[qt][jf][r]);

    // pack to bf16 A-fragments (K=32 contraction block = this wave's j-slice)
    short8 pf[4];
#pragma unroll
    for (int qt = 0; qt < 4; ++qt)
      pf[qt] = mk8(cvtpk(w[qt][0][0], w[qt][0][1]),
                   cvtpk(w[qt][0][2], w[qt][0][3]),
                   cvtpk(w[qt][1][0], w[qt][1][1]),
                   cvtpk(w[qt][1][2], w[qt][1][3]));

    // PV over the slice + ones row-sum, 20 MFMA
    __builtin_amdgcn_s_setprio(1);
#pragma unroll
    for (int qt = 0; qt < 4; ++qt) {
#pragma unroll
      for (int df = 0; df < 4; ++df)
        acc[qt][df] = __builtin_amdgcn_mfma_f32_16x16x32_bf16(pf[qt], vf[df], acc[qt][df], 0, 0, 0);
      lacc[qt] = __builtin_amdgcn_mfma_f32_16x16x32_bf16(pf[qt], onesb, lacc[qt], 0, 0, 0);
    }
    __builtin_amdgcn_s_setprio(0);
  }

  // ---- epilogue: combine jw partials via LDS (reuse K/V buffers), then write ----
  __syncthreads();
  float* cb = (float*)lds;
  const int cbase = qw * 5120;  // floats; 20 KB per qw, 40 KB total
  if (jw == 1) {
#pragma unroll
    for (int qt = 0; qt < 4; ++qt) {
#pragma unroll
      for (int df = 0; df < 4; ++df)
        *(f32x4*)&cb[cbase + ((qt * 4 + df) * 64 + lane) * 4] = acc[qt][df];
      *(f32x4*)&cb[cbase + 4096 + (qt * 64 + lane) * 4] = lacc[qt];
    }
  }
  __syncthreads();
  if (jw == 0) {
#pragma unroll
    for (int qt = 0; qt < 4; ++qt) {
#pragma unroll
      for (int df = 0; df < 4; ++df)
        acc[qt][df] += *(const f32x4*)&cb[cbase + ((qt * 4 + df) * 64 + lane) * 4];
      lacc[qt] += *(const f32x4*)&cb[cbase + 4096 + (qt * 64 + lane) * 4];
    }
#pragma unroll
    for (int qt = 0; qt < 4; ++qt)
#pragma unroll
      for (int r = 0; r < 4; ++r) {
        float inv = 1.f / lacc[qt][r];
        int row = q0 + qt * 16 + g * 4 + r;
#pragma unroll
        for (int df = 0; df < 4; ++df)
          aT[((size_t)bb * 4096 + row) * 512 + h * 64 + df * 16 + ln] =
              f2bf(acc[qt][df][r] * inv);
      }
  }
}

// ---------------- launcher ----------------
extern "C" void kernel_launch(void* const* d_in, const int* in_sizes, int n_in,
                              void* d_out, int out_size, void* d_ws, size_t ws_size,
                              hipStream_t stream) {
  const float* x     = (const float*)d_in[0];
  const float* gnw   = (const float*)d_in[1];
  const float* gnb   = (const float*)d_in[2];
  const float* qkvw  = (const float*)d_in[3];
  const float* qkvb  = (const float*)d_in[4];
  const float* projw = (const float*)d_in[5];
  const float* projb = (const float*)d_in[6];
  float* out = (float*)d_out;
  char* ws = (char*)d_ws;

  const size_t OFF_WQ   = 0;
  const size_t OFF_WP   = 1572864;
  const size_t OFF_XN   = 2097152;
  const size_t OFF_XNT  = 10485760;
  const size_t OFF_QKV  = 18874368;
  const size_t OFF_QKVT = 44040192;
  const size_t OFF_AT   = 69206016;
  const size_t OFF_PART = 77594624;
  const size_t OFF_STAT = 77602816;

  unsigned short* wq   = (unsigned short*)(ws + OFF_WQ);
  unsigned short* wp   = (unsigned short*)(ws + OFF_WP);
  unsigned short* xn   = (unsigned short*)(ws + OFF_XN);
  unsigned short* xnT  = (unsigned short*)(ws + OFF_XNT);
  unsigned short* qkv  = (unsigned short*)(ws + OFF_QKV);
  unsigned short* qkvT = (unsigned short*)(ws + OFF_QKVT);
  unsigned short* aT   = (unsigned short*)(ws + OFF_AT);
  float* part  = (float*)(ws + OFF_PART);
  float* stats = (float*)(ws + OFF_STAT);

  k_wgn<<<dim3(2048), dim3(256), 0, stream>>>(qkvw, projw, wq, wp, x, part);
  k_gnfin<<<dim3(1), dim3(64), 0, stream>>>(part, stats);
  k_gnnorm<<<dim3(64, 8, 2), dim3(256), 0, stream>>>(x, gnw, gnb, stats, xn, xnT);
  k_gemm<0><<<dim3(32, 12, 2), dim3(256), 0, stream>>>(wq, xnT, qkvb, qkv, qkvT, nullptr, nullptr, 1536);
  k_attn<<<dim3(32, 8, 2), dim3(256), 0, stream>>>(qkv, qkvT, aT);
  k_gemm<1><<<dim3(32, 4, 2), dim3(256), 0, stream>>>(wp, aT, projb, nullptr, nullptr, xn, out, 512);
}